// Round 7
// baseline (237.133 us; speedup 1.0000x reference)
//
#include <hip/hip_runtime.h>
#include <hip/hip_fp16.h>
#include <math.h>

#define NEG_SLOPE 0.2f
#define BSHIFT 6         // 64-node buckets
#define BNODES 64
#define MAXB 1056        // >= nbuckets = ceil(N/64) = 1034
#define CAP 2816         // records per bucket region; mean 1936, sigma 44 (+20 sigma)
#define BIN_E 2048       // edges per bin block

typedef unsigned short ushort8_v __attribute__((ext_vector_type(8)));
typedef short  short8_v  __attribute__((ext_vector_type(8)));
typedef float  float4_v  __attribute__((ext_vector_type(4)));

__device__ __forceinline__ unsigned short f2bf(float f) {
    unsigned u = __float_as_uint(f);
    u = (u + 0x7FFFu + ((u >> 16) & 1u)) >> 16;    // round-nearest-even
    return (unsigned short)u;
}
__device__ __forceinline__ float bf2f(unsigned short b) {
    return __uint_as_float(((unsigned)b) << 16);
}
__device__ __forceinline__ float lrelu(float x) {
    return x > 0.f ? x : NEG_SLOPE * x;
}
__device__ __forceinline__ unsigned f2h_bits(float f) {
    __half_raw hr = __half_raw(__float2half_rn(f));
    return (unsigned)hr.x;
}
__device__ __forceinline__ float h2f_bits(unsigned short u) {
    __half_raw hr; hr.x = u;
    return __half2float(__half(hr));
}

// ---------------------------------------------------------------------------
// K1 (fused, Bresenham-interleaved roles): bin blocks build 4B records
//   rec = src | (dst&63)<<17
// via LDS counting-sort into FIXED-CAPACITY bucket regions stage[b*CAP ...]
// (bucket bases arithmetic; tails[b] counts from 0). Transform blocks:
// node MFMA transform (h = x@W bf16, f32 accum) + attention logits; hb
// staged in LDS, coalesced 16B flush. Roles Bresenham-interleaved so both
// kinds are co-resident from dispatch 0.
// LDS union: tile 33.3KB vs bin 29.2KB -> 33.3KB static, 4 blocks/CU.
// Layouts (verified m89/m91/m120): A[m=lane&15][k=quad*8+j],
// B[k=quad*8+j][n=lane&15], C: col=lane&15, row=quad*4+reg.
// ---------------------------------------------------------------------------
__global__ __launch_bounds__(512) void k_xform_bin(
        const float* __restrict__ users,
        const float* __restrict__ items,
        const float* __restrict__ W,
        const float* __restrict__ att_src,
        const float* __restrict__ att_dst,
        unsigned short* __restrict__ hb,
        float* __restrict__ a_src,
        float* __restrict__ a_dst,
        const int* __restrict__ src,
        const int* __restrict__ dst,
        int* __restrict__ tails,
        int* __restrict__ stage_g,
        int nedges, int nbuckets, int n_users, int N,
        int nxf, int ntotal)
{
    __shared__ __align__(16) char smem[128 * 130 * 2];   // 33280 B

    const int tid  = threadIdx.x;          // 0..511
    const int lane = tid & 63;
    const int wid  = tid >> 6;             // 0..7

    // Bresenham role split: exactly nxf transform blocks, evenly interleaved
    const int bid = blockIdx.x;
    const long long num = (long long)nxf;
    const int xf_before = (int)(((long long)bid * num) / ntotal);
    const bool is_xf = ((((long long)(bid + 1) * num) / ntotal) > xf_before);

    if (!is_xf) {
        // ---------------- bin part ----------------
        const int bin_id = bid - xf_before;
        int* cnt     = (int*)smem;                 // [MAXB]
        int* runoff  = cnt + MAXB;
        int* cursor  = runoff + MAXB;
        int* runbase = cursor + MAXB;
        int* stage   = runbase + MAXB;             // [BIN_E]
        unsigned short* sb = (unsigned short*)(stage + BIN_E);  // [BIN_E]

        const int base = bin_id * BIN_E;
        const int nvalid = min(BIN_E, nedges - base);

        for (int i = tid; i < nbuckets; i += 512) cnt[i] = 0;
        __syncthreads();

        int myrec[BIN_E / 512];
        int myb[BIN_E / 512];
        #pragma unroll
        for (int k = 0; k < BIN_E / 512; ++k) {
            int i = base + k * 512 + tid;
            if (i < nedges) {
                const int d = dst[i];
                myrec[k] = src[i] | ((d & (BNODES - 1)) << 17);
                myb[k] = d >> BSHIFT;
                atomicAdd(&cnt[myb[k]], 1);
            } else {
                myb[k] = -1;
            }
        }
        __syncthreads();

        if (wid == 0) {
            int running = 0;
            for (int b2 = 0; b2 < nbuckets; b2 += 64) {
                int idx = b2 + lane;
                int v = (idx < nbuckets) ? cnt[idx] : 0;
                int incl = v;
                #pragma unroll
                for (int off = 1; off < 64; off <<= 1) {
                    int t = __shfl_up(incl, off);
                    if (lane >= off) incl += t;
                }
                if (idx < nbuckets) runoff[idx] = running + incl - v;
                running += __shfl(incl, 63);
            }
        }
        __syncthreads();

        for (int i = tid; i < nbuckets; i += 512) cursor[i] = runoff[i];
        __syncthreads();

        #pragma unroll
        for (int k = 0; k < BIN_E / 512; ++k) {
            if (myb[k] >= 0) {
                int pos = atomicAdd(&cursor[myb[k]], 1);
                stage[pos] = myrec[k];
                sb[pos] = (unsigned short)myb[k];
            }
        }

        for (int i = tid; i < nbuckets; i += 512)
            if (cnt[i] > 0) runbase[i] = atomicAdd(&tails[i], cnt[i]);
        __syncthreads();

        for (int i = tid; i < nvalid; i += 512) {
            const int b = sb[i];
            const int idx = runbase[b] + (i - runoff[b]);
            if (idx < CAP)
                stage_g[(size_t)b * CAP + idx] = stage[i];
        }
        return;
    }

    // ---------------- transform part ----------------
    unsigned short (*tile)[130] = (unsigned short (*)[130])smem;
    const int blk  = xf_before;              // transform block id 0..nxf-1
    const int quad = lane >> 4;              // 0..3
    const int l16  = lane & 15;
    const int tb   = blk * 128 + wid * 16;   // tile base node

    // B fragments: bfrag[t][h2] holds W[k = h2*32+quad*8+j][t*16 + l16]
    short8_v bfrag[8][2];
    #pragma unroll
    for (int t = 0; t < 8; ++t)
        #pragma unroll
        for (int h2 = 0; h2 < 2; ++h2)
            #pragma unroll
            for (int j = 0; j < 8; ++j)
                bfrag[t][h2][j] = (short)f2bf(
                    W[(h2 * 32 + quad * 8 + j) * 128 + t * 16 + l16]);

    float atts[8], attd[8];
    #pragma unroll
    for (int t = 0; t < 8; ++t) {
        atts[t] = att_src[t * 16 + l16];
        attd[t] = att_dst[t * 16 + l16];
    }

    const int arow = tb + l16;
    short8_v a0 = (short8_v)0, a1 = (short8_v)0;
    if (arow < N) {
        const float* xr = (arow < n_users)
            ? (users + (size_t)arow * 64)
            : (items + (size_t)(arow - n_users) * 64);
        const float4_v x0 = *reinterpret_cast<const float4_v*>(xr + quad * 8);
        const float4_v x1 = *reinterpret_cast<const float4_v*>(xr + quad * 8 + 4);
        const float4_v x2 = *reinterpret_cast<const float4_v*>(xr + 32 + quad * 8);
        const float4_v x3 = *reinterpret_cast<const float4_v*>(xr + 32 + quad * 8 + 4);
        #pragma unroll
        for (int j = 0; j < 4; ++j) {
            a0[j]     = (short)f2bf(x0[j]);
            a0[j + 4] = (short)f2bf(x1[j]);
            a1[j]     = (short)f2bf(x2[j]);
            a1[j + 4] = (short)f2bf(x3[j]);
        }
    }

    float4_v acc[8];
    #pragma unroll
    for (int t = 0; t < 8; ++t) {
        acc[t] = (float4_v)0.f;
        acc[t] = __builtin_amdgcn_mfma_f32_16x16x32_bf16(a0, bfrag[t][0], acc[t], 0, 0, 0);
        acc[t] = __builtin_amdgcn_mfma_f32_16x16x32_bf16(a1, bfrag[t][1], acc[t], 0, 0, 0);
    }

    const int wrow0 = tb + quad * 4;
    float s0[4] = {0,0,0,0}, s1[4] = {0,0,0,0};
    float d0[4] = {0,0,0,0}, d1[4] = {0,0,0,0};
    #pragma unroll
    for (int t = 0; t < 8; ++t) {
        #pragma unroll
        for (int r = 0; r < 4; ++r) {
            const float v = acc[t][r];
            if (t < 4) { s0[r] = fmaf(v, atts[t], s0[r]);
                         d0[r] = fmaf(v, attd[t], d0[r]); }
            else       { s1[r] = fmaf(v, atts[t], s1[r]);
                         d1[r] = fmaf(v, attd[t], d1[r]); }
            tile[wid * 16 + quad * 4 + r][t * 16 + l16] = f2bf(v);
        }
    }

    #pragma unroll
    for (int off = 1; off < 16; off <<= 1) {
        #pragma unroll
        for (int r = 0; r < 4; ++r) {
            s0[r] += __shfl_xor(s0[r], off);
            s1[r] += __shfl_xor(s1[r], off);
            d0[r] += __shfl_xor(d0[r], off);
            d1[r] += __shfl_xor(d1[r], off);
        }
    }
    if (l16 == 0) {
        #pragma unroll
        for (int r = 0; r < 4; ++r) {
            const int row = wrow0 + r;
            if (row < N) {
                a_src[row * 2]     = s0[r];
                a_src[row * 2 + 1] = s1[r];
                a_dst[row * 2]     = d0[r];
                a_dst[row * 2 + 1] = d1[r];
            }
        }
    }

    // coalesced hb flush: 16B per lane
    __syncthreads();
    const int base_node = blk * 128;
    const int nrem = min(128, N - base_node);
    for (int k = tid; k < nrem * 16; k += 512) {
        const int n = k >> 4, g = k & 15;
        ushort8_v v;
        #pragma unroll
        for (int j = 0; j < 8; ++j) v[j] = tile[n][g * 8 + j];
        *reinterpret_cast<ushort8_v*>(
            hb + (size_t)(base_node + n) * 128 + g * 8) = v;
    }
}

// ---------------------------------------------------------------------------
// K2: fused within-bucket sort + gather. Round-6 lesson: at 128-node
// buckets this was 517 blocks = 2.02 blocks/CU -> two sequential rounds,
// no tail fill, sort phases poorly hidden (99us @ 57% occupancy vs
// round-2's 71us @ 71%). Now: 64-node buckets, 512 thr (8 waves),
// LDS ~35KB -> 4 blocks/CU = 32 waves/CU, 1034 blocks = 4.04 rounds --
// 3 of 4 co-resident blocks gather while 1 sorts.
// Phase 1: read bucket once -> lin[] + per-node histogram. Phase 2: exp
// once per edge (a_src L2 gather + LDS a_dst), pack f16x2, scatter
// int2{exbits,src} into per-node order in LDS. Phase 3: verified
// quarter-wave gather loop (byte-identical inner chain).
// ---------------------------------------------------------------------------
__global__ __launch_bounds__(512) void k_sort_gather(
        const int* __restrict__ stage_g,
        const int* __restrict__ tails,
        const float* __restrict__ a_src,
        const float* __restrict__ a_dst,
        const unsigned short* __restrict__ hb,
        const float* __restrict__ bias,
        float* __restrict__ out,
        int N)
{
    __shared__ int cnt[BNODES];
    __shared__ int off[BNODES];
    __shared__ int cursor[BNODES];
    __shared__ float adst[BNODES][2];
    __shared__ int lin[CAP];
    __shared__ int2 lsorted[CAP];

    const int b    = blockIdx.x;
    const int tid  = threadIdx.x;          // 0..511
    const int lane = tid & 63;
    const int wid  = tid >> 6;             // 0..7
    const int node0  = b << BSHIFT;
    const int nnodes = min(BNODES, N - node0);
    const int nrec = min(tails[b], CAP);
    const int* bucket = stage_g + (size_t)b * CAP;

    if (tid < BNODES) {
        cnt[tid] = 0;
        if (tid < nnodes) {
            const float2 ad = *reinterpret_cast<const float2*>(
                a_dst + 2 * (node0 + tid));
            adst[tid][0] = ad.x;
            adst[tid][1] = ad.y;
        } else {
            adst[tid][0] = adst[tid][1] = 0.f;
        }
    }
    __syncthreads();

    // phase 1: single global pass -> lin[] + per-node histogram
    for (int i = tid; i < nrec; i += 512) {
        const int r = bucket[i];
        lin[i] = r;
        atomicAdd(&cnt[(r >> 17) & (BNODES - 1)], 1);
    }
    __syncthreads();

    if (wid == 0) {
        const int v = cnt[lane];
        int incl = v;
        #pragma unroll
        for (int o = 1; o < 64; o <<= 1) {
            int t = __shfl_up(incl, o);
            if (lane >= o) incl += t;
        }
        off[lane] = incl - v;
        cursor[lane] = incl - v;
    }
    __syncthreads();

    // phase 2: exp once per edge + scatter into per-node order in LDS
    for (int i = tid; i < nrec; i += 512) {
        const int r = lin[i];
        const int s = r & 0x1FFFF;
        const int n = (r >> 17) & (BNODES - 1);
        const float2 as2 = *reinterpret_cast<const float2*>(a_src + 2 * s);
        const unsigned e0 = f2h_bits(__expf(lrelu(as2.x + adst[n][0])));
        const unsigned e1 = f2h_bits(__expf(lrelu(as2.y + adst[n][1])));
        const int pos = atomicAdd(&cursor[n], 1);
        if (pos < CAP) {
            int2 rec;
            rec.x = (int)((e1 << 16) | e0);
            rec.y = s;
            lsorted[pos] = rec;
        }
    }
    __syncthreads();

    // phase 3: gather -- wave per node, quarter-wave per edge, 4 in flight
    // + unroll 4. Lane sl owns channels sl*8..sl*8+7. (round-4 verified)
    const int q  = lane >> 4;
    const int sl = lane & 15;
    const int hd = sl >> 3;

    for (int n = wid; n < nnodes; n += 8) {
        const int d = node0 + n;
        const float2 as2 = *reinterpret_cast<const float2*>(a_src + 2 * d);
        const float exs0 = __expf(lrelu(as2.x + adst[n][0]));
        const float exs1 = __expf(lrelu(as2.y + adst[n][1]));
        const int start = off[n];
        const int cnt1  = cnt[n] + 1;      // +1 for self loop

        float acc[8];
        #pragma unroll
        for (int i = 0; i < 8; ++i) acc[i] = 0.f;
        float den = 0.f;

        #pragma unroll 4
        for (int v = q; v < cnt1; v += 4) {
            int s; float ex;
            if (v == 0) {
                s = d;  ex = hd ? exs1 : exs0;
            } else {
                const int2 r = lsorted[start + v - 1];
                s = r.y;
                const unsigned eb = (unsigned)r.x;
                ex = h2f_bits(hd ? (unsigned short)(eb >> 16)
                                 : (unsigned short)(eb & 0xFFFFu));
            }
            const ushort8_v hv = *reinterpret_cast<const ushort8_v*>(
                hb + (size_t)s * 128 + sl * 8);
            den += ex;
            #pragma unroll
            for (int i = 0; i < 8; ++i)
                acc[i] = fmaf(ex, bf2f(hv[i]), acc[i]);
        }

        #pragma unroll
        for (int o = 16; o <= 32; o <<= 1) {
            #pragma unroll
            for (int i = 0; i < 8; ++i) acc[i] += __shfl_xor(acc[i], o);
            den += __shfl_xor(den, o);
        }

        if (q == 0) {
            const float inv = 1.f / (den + 1e-16f);
            float4 o0, o1;
            o0.x = acc[0] * inv + bias[sl * 8 + 0];
            o0.y = acc[1] * inv + bias[sl * 8 + 1];
            o0.z = acc[2] * inv + bias[sl * 8 + 2];
            o0.w = acc[3] * inv + bias[sl * 8 + 3];
            o1.x = acc[4] * inv + bias[sl * 8 + 4];
            o1.y = acc[5] * inv + bias[sl * 8 + 5];
            o1.z = acc[6] * inv + bias[sl * 8 + 6];
            o1.w = acc[7] * inv + bias[sl * 8 + 7];
            float* op = out + (size_t)d * 128 + sl * 8;
            *reinterpret_cast<float4*>(op)     = o0;
            *reinterpret_cast<float4*>(op + 4) = o1;
        }
    }
}

extern "C" void kernel_launch(void* const* d_in, const int* in_sizes, int n_in,
                              void* d_out, int out_size, void* d_ws, size_t ws_size,
                              hipStream_t stream) {
    const int*   edge  = (const int*)  d_in[0];   // (2,E) int32
    const float* users = (const float*)d_in[1];   // (N_USERS,64) f32
    const float* items = (const float*)d_in[2];   // (N_ITEMS,64) f32
    const float* W     = (const float*)d_in[3];   // (64,128) f32
    const float* att_s = (const float*)d_in[4];   // (2,64) f32
    const float* att_d = (const float*)d_in[5];   // (2,64) f32
    const float* bias  = (const float*)d_in[6];   // (128,) f32

    const int E       = in_sizes[0] / 2;
    const int n_users = in_sizes[1] / 64;
    const int n_items = in_sizes[2] / 64;
    const int N       = n_users + n_items;
    const int nbuckets = (N + BNODES - 1) >> BSHIFT;   // 1034

    float* out = (float*)d_out;

    // Workspace layout (8-B alignment maintained):
    // hb (N*128 bf16) | stage (MAXB*CAP int, fixed-capacity regions)
    // | a_src | a_dst | tails
    char* ws = (char*)d_ws;
    unsigned short* hb = (unsigned short*)ws;
    ws += (size_t)N * 128 * sizeof(unsigned short);
    int*   stage    = (int*)ws;    ws += (size_t)MAXB * CAP * sizeof(int);
    float* a_src    = (float*)ws;  ws += (size_t)N * 2 * sizeof(float);
    float* a_dst    = (float*)ws;  ws += (size_t)N * 2 * sizeof(float);
    int*   tails    = (int*)ws;

    const int* src = edge;
    const int* dst = edge + E;

    hipMemsetAsync(tails, 0, MAXB * sizeof(int), stream);

    const int nbin = (E + BIN_E - 1) / BIN_E;          // 977
    const int nxf  = (N + 127) / 128;                  // 517
    const int ntotal = nbin + nxf;
    k_xform_bin<<<ntotal, 512, 0, stream>>>(
        users, items, W, att_s, att_d, hb, a_src, a_dst,
        src, dst, tails, stage, E, nbuckets, n_users, N, nxf, ntotal);

    k_sort_gather<<<nbuckets, 512, 0, stream>>>(
        stage, tails, a_src, a_dst, hb, bias, out, N);
}

// Round 8
// 228.597 us; speedup vs baseline: 1.0373x; 1.0373x over previous
//
#include <hip/hip_runtime.h>
#include <hip/hip_fp16.h>
#include <math.h>

#define NEG_SLOPE 0.2f
#define BSHIFT 6         // 64-node buckets
#define BNODES 64
#define MAXB 1056        // >= nbuckets = ceil(N/64) = 1034
#define CAP 2816         // records per bucket region; mean 1936, sigma 44 (+20 sigma)
#define BIN_E 4096       // edges per bin block (round-7 lesson: 2048 -> 2-rec
                         // bursts + 870K device atomics; 4096 halves both)
#define NKEY 1024        // sort keys in sg: node(6b) * 16 + src-slice(4b)

typedef unsigned short ushort8_v __attribute__((ext_vector_type(8)));
typedef short  short8_v  __attribute__((ext_vector_type(8)));
typedef float  float4_v  __attribute__((ext_vector_type(4)));

__device__ __forceinline__ unsigned short f2bf(float f) {
    unsigned u = __float_as_uint(f);
    u = (u + 0x7FFFu + ((u >> 16) & 1u)) >> 16;    // round-nearest-even
    return (unsigned short)u;
}
__device__ __forceinline__ float bf2f(unsigned short b) {
    return __uint_as_float(((unsigned)b) << 16);
}
__device__ __forceinline__ float lrelu(float x) {
    return x > 0.f ? x : NEG_SLOPE * x;
}
__device__ __forceinline__ unsigned f2h_bits(float f) {
    __half_raw hr = __half_raw(__float2half_rn(f));
    return (unsigned)hr.x;
}
__device__ __forceinline__ float h2f_bits(unsigned short u) {
    __half_raw hr; hr.x = u;
    return __half2float(__half(hr));
}

// ---------------------------------------------------------------------------
// K1 (fused, Bresenham-interleaved roles): bin blocks build 4B records
//   rec = src | (dst&63)<<17
// via LDS counting-sort (4096 edges/block) into fixed-capacity bucket
// regions stage[b*CAP...]; ~1 device atomic per (block, nonempty bucket).
// runbase folded into runoff as a shift (idx = shift[b] + local_pos) to fit
// LDS. Transform blocks: node MFMA transform + attention logits; hb staged
// in LDS, coalesced 16B flush. Bresenham interleave keeps both roles
// co-resident from dispatch 0.
// LDS union: bin 37.2KB vs tile 33.3KB -> 37.2KB static, 4 blocks/CU.
// Layouts (verified m89/m91/m120): A[m=lane&15][k=quad*8+j],
// B[k=quad*8+j][n=lane&15], C: col=lane&15, row=quad*4+reg.
// ---------------------------------------------------------------------------
__global__ __launch_bounds__(512) void k_xform_bin(
        const float* __restrict__ users,
        const float* __restrict__ items,
        const float* __restrict__ W,
        const float* __restrict__ att_src,
        const float* __restrict__ att_dst,
        unsigned short* __restrict__ hb,
        float* __restrict__ a_src,
        float* __restrict__ a_dst,
        const int* __restrict__ src,
        const int* __restrict__ dst,
        int* __restrict__ tails,
        int* __restrict__ stage_g,
        int nedges, int nbuckets, int n_users, int N,
        int nxf, int ntotal)
{
    __shared__ __align__(16) char smem[3 * MAXB * 4 + BIN_E * 4 + BIN_E * 2];

    const int tid  = threadIdx.x;          // 0..511
    const int lane = tid & 63;
    const int wid  = tid >> 6;             // 0..7

    // Bresenham role split: exactly nxf transform blocks, evenly interleaved
    const int bid = blockIdx.x;
    const long long num = (long long)nxf;
    const int xf_before = (int)(((long long)bid * num) / ntotal);
    const bool is_xf = ((((long long)(bid + 1) * num) / ntotal) > xf_before);

    if (!is_xf) {
        // ---------------- bin part ----------------
        const int bin_id = bid - xf_before;
        int* cnt     = (int*)smem;                 // [MAXB]
        int* runoff  = cnt + MAXB;                 // becomes shift later
        int* cursor  = runoff + MAXB;
        int* stage   = cursor + MAXB;              // [BIN_E]
        unsigned short* sb = (unsigned short*)(stage + BIN_E);  // [BIN_E]

        const int base = bin_id * BIN_E;
        const int nvalid = min(BIN_E, nedges - base);

        for (int i = tid; i < nbuckets; i += 512) cnt[i] = 0;
        __syncthreads();

        int myrec[BIN_E / 512];
        int myb[BIN_E / 512];
        #pragma unroll
        for (int k = 0; k < BIN_E / 512; ++k) {
            int i = base + k * 512 + tid;
            if (i < nedges) {
                const int d = dst[i];
                myrec[k] = src[i] | ((d & (BNODES - 1)) << 17);
                myb[k] = d >> BSHIFT;
                atomicAdd(&cnt[myb[k]], 1);
            } else {
                myb[k] = -1;
            }
        }
        __syncthreads();

        if (wid == 0) {
            int running = 0;
            for (int b2 = 0; b2 < nbuckets; b2 += 64) {
                int idx = b2 + lane;
                int v = (idx < nbuckets) ? cnt[idx] : 0;
                int incl = v;
                #pragma unroll
                for (int off = 1; off < 64; off <<= 1) {
                    int t = __shfl_up(incl, off);
                    if (lane >= off) incl += t;
                }
                if (idx < nbuckets) runoff[idx] = running + incl - v;
                running += __shfl(incl, 63);
            }
        }
        __syncthreads();

        for (int i = tid; i < nbuckets; i += 512) cursor[i] = runoff[i];
        __syncthreads();

        #pragma unroll
        for (int k = 0; k < BIN_E / 512; ++k) {
            if (myb[k] >= 0) {
                int pos = atomicAdd(&cursor[myb[k]], 1);
                stage[pos] = myrec[k];
                sb[pos] = (unsigned short)myb[k];
            }
        }

        // tails bump + fold runbase into runoff: shift = runbase - runoff
        for (int i = tid; i < nbuckets; i += 512)
            if (cnt[i] > 0) {
                const int rb = atomicAdd(&tails[i], cnt[i]);
                runoff[i] = rb - runoff[i];
            }
        __syncthreads();

        for (int i = tid; i < nvalid; i += 512) {
            const int b = sb[i];
            const int idx = runoff[b] + i;         // shift + local pos
            if (idx < CAP)
                stage_g[(size_t)b * CAP + idx] = stage[i];
        }
        return;
    }

    // ---------------- transform part ----------------
    unsigned short (*tile)[130] = (unsigned short (*)[130])smem;
    const int blk  = xf_before;              // transform block id 0..nxf-1
    const int quad = lane >> 4;              // 0..3
    const int l16  = lane & 15;
    const int tb   = blk * 128 + wid * 16;   // tile base node

    // B fragments: bfrag[t][h2] holds W[k = h2*32+quad*8+j][t*16 + l16]
    short8_v bfrag[8][2];
    #pragma unroll
    for (int t = 0; t < 8; ++t)
        #pragma unroll
        for (int h2 = 0; h2 < 2; ++h2)
            #pragma unroll
            for (int j = 0; j < 8; ++j)
                bfrag[t][h2][j] = (short)f2bf(
                    W[(h2 * 32 + quad * 8 + j) * 128 + t * 16 + l16]);

    float atts[8], attd[8];
    #pragma unroll
    for (int t = 0; t < 8; ++t) {
        atts[t] = att_src[t * 16 + l16];
        attd[t] = att_dst[t * 16 + l16];
    }

    const int arow = tb + l16;
    short8_v a0 = (short8_v)0, a1 = (short8_v)0;
    if (arow < N) {
        const float* xr = (arow < n_users)
            ? (users + (size_t)arow * 64)
            : (items + (size_t)(arow - n_users) * 64);
        const float4_v x0 = *reinterpret_cast<const float4_v*>(xr + quad * 8);
        const float4_v x1 = *reinterpret_cast<const float4_v*>(xr + quad * 8 + 4);
        const float4_v x2 = *reinterpret_cast<const float4_v*>(xr + 32 + quad * 8);
        const float4_v x3 = *reinterpret_cast<const float4_v*>(xr + 32 + quad * 8 + 4);
        #pragma unroll
        for (int j = 0; j < 4; ++j) {
            a0[j]     = (short)f2bf(x0[j]);
            a0[j + 4] = (short)f2bf(x1[j]);
            a1[j]     = (short)f2bf(x2[j]);
            a1[j + 4] = (short)f2bf(x3[j]);
        }
    }

    float4_v acc[8];
    #pragma unroll
    for (int t = 0; t < 8; ++t) {
        acc[t] = (float4_v)0.f;
        acc[t] = __builtin_amdgcn_mfma_f32_16x16x32_bf16(a0, bfrag[t][0], acc[t], 0, 0, 0);
        acc[t] = __builtin_amdgcn_mfma_f32_16x16x32_bf16(a1, bfrag[t][1], acc[t], 0, 0, 0);
    }

    const int wrow0 = tb + quad * 4;
    float s0[4] = {0,0,0,0}, s1[4] = {0,0,0,0};
    float d0[4] = {0,0,0,0}, d1[4] = {0,0,0,0};
    #pragma unroll
    for (int t = 0; t < 8; ++t) {
        #pragma unroll
        for (int r = 0; r < 4; ++r) {
            const float v = acc[t][r];
            if (t < 4) { s0[r] = fmaf(v, atts[t], s0[r]);
                         d0[r] = fmaf(v, attd[t], d0[r]); }
            else       { s1[r] = fmaf(v, atts[t], s1[r]);
                         d1[r] = fmaf(v, attd[t], d1[r]); }
            tile[wid * 16 + quad * 4 + r][t * 16 + l16] = f2bf(v);
        }
    }

    #pragma unroll
    for (int off = 1; off < 16; off <<= 1) {
        #pragma unroll
        for (int r = 0; r < 4; ++r) {
            s0[r] += __shfl_xor(s0[r], off);
            s1[r] += __shfl_xor(s1[r], off);
            d0[r] += __shfl_xor(d0[r], off);
            d1[r] += __shfl_xor(d1[r], off);
        }
    }
    if (l16 == 0) {
        #pragma unroll
        for (int r = 0; r < 4; ++r) {
            const int row = wrow0 + r;
            if (row < N) {
                a_src[row * 2]     = s0[r];
                a_src[row * 2 + 1] = s1[r];
                a_dst[row * 2]     = d0[r];
                a_dst[row * 2 + 1] = d1[r];
            }
        }
    }

    // coalesced hb flush: 16B per lane
    __syncthreads();
    const int base_node = blk * 128;
    const int nrem = min(128, N - base_node);
    for (int k = tid; k < nrem * 16; k += 512) {
        const int n = k >> 4, g = k & 15;
        ushort8_v v;
        #pragma unroll
        for (int j = 0; j < 8; ++j) v[j] = tile[n][g * 8 + j];
        *reinterpret_cast<ushort8_v*>(
            hb + (size_t)(base_node + n) * 128 + g * 8) = v;
    }
}

// ---------------------------------------------------------------------------
// K2: fused within-bucket sort + gather. 64-node buckets, 512 thr (8 waves),
// 4 blocks/CU. NEW: sort key = node*16 + src-slice (src>>13, 2MB hb slices).
// The gather loop is unchanged, but each node's edges are traversed in
// ascending 2MB src-slices and ALL blocks walk slices in the same order ->
// the per-XCD 4MB L2 holds the ~2 active slices -> hb hit rate up (round-7
// FETCH was 209MB = 59% hit on 512MB raw row demand). lin[] dropped (phase
// 2 re-reads stage L2-hot, round-6-proven) to keep LDS 34.5KB / 4 blocks.
// Phase 2: exp once per edge, pack f16x2, scatter int2{exbits,src} into
// (node,slice) order in LDS. Phase 3: verified quarter-wave gather loop.
// ---------------------------------------------------------------------------
__global__ __launch_bounds__(512) void k_sort_gather(
        const int* __restrict__ stage_g,
        const int* __restrict__ tails,
        const float* __restrict__ a_src,
        const float* __restrict__ a_dst,
        const unsigned short* __restrict__ hb,
        const float* __restrict__ bias,
        float* __restrict__ out,
        int N)
{
    __shared__ int cnt[NKEY];
    __shared__ int off[NKEY + 1];
    __shared__ int cursor[NKEY];
    __shared__ float adst[BNODES][2];
    __shared__ int2 lsorted[CAP];

    const int b    = blockIdx.x;
    const int tid  = threadIdx.x;          // 0..511
    const int lane = tid & 63;
    const int wid  = tid >> 6;             // 0..7
    const int node0  = b << BSHIFT;
    const int nnodes = min(BNODES, N - node0);
    const int nrec = min(tails[b], CAP);
    const int* bucket = stage_g + (size_t)b * CAP;

    for (int i = tid; i < NKEY; i += 512) cnt[i] = 0;
    if (tid < BNODES) {
        if (tid < nnodes) {
            const float2 ad = *reinterpret_cast<const float2*>(
                a_dst + 2 * (node0 + tid));
            adst[tid][0] = ad.x;
            adst[tid][1] = ad.y;
        } else {
            adst[tid][0] = adst[tid][1] = 0.f;
        }
    }
    __syncthreads();

    // phase 1: histogram over (node, src-slice) keys
    for (int i = tid; i < nrec; i += 512) {
        const int r = bucket[i];
        const int key = (((r >> 17) & (BNODES - 1)) << 4) | ((r & 0x1FFFF) >> 13);
        atomicAdd(&cnt[key], 1);
    }
    __syncthreads();

    // wave 0: exclusive scan over 1024 keys (16 chunks)
    if (wid == 0) {
        int running = 0;
        #pragma unroll
        for (int c = 0; c < NKEY; c += 64) {
            const int v = cnt[c + lane];
            int incl = v;
            #pragma unroll
            for (int o = 1; o < 64; o <<= 1) {
                int t = __shfl_up(incl, o);
                if (lane >= o) incl += t;
            }
            off[c + lane] = running + incl - v;
            running += __shfl(incl, 63);
        }
        if (lane == 0) off[NKEY] = running;
    }
    __syncthreads();
    for (int i = tid; i < NKEY; i += 512) cursor[i] = off[i];
    __syncthreads();

    // phase 2: L2-hot re-read; exp once per edge; scatter into LDS order
    for (int i = tid; i < nrec; i += 512) {
        const int r = bucket[i];
        const int s = r & 0x1FFFF;
        const int n = (r >> 17) & (BNODES - 1);
        const int key = (n << 4) | (s >> 13);
        const float2 as2 = *reinterpret_cast<const float2*>(a_src + 2 * s);
        const unsigned e0 = f2h_bits(__expf(lrelu(as2.x + adst[n][0])));
        const unsigned e1 = f2h_bits(__expf(lrelu(as2.y + adst[n][1])));
        const int pos = atomicAdd(&cursor[key], 1);
        if (pos < CAP) {
            int2 rec;
            rec.x = (int)((e1 << 16) | e0);
            rec.y = s;
            lsorted[pos] = rec;
        }
    }
    __syncthreads();

    // phase 3: gather -- wave per node, quarter-wave per edge, 4 in flight
    // + unroll 4. Lane sl owns channels sl*8..sl*8+7. (round-4 verified)
    const int q  = lane >> 4;
    const int sl = lane & 15;
    const int hd = sl >> 3;

    for (int n = wid; n < nnodes; n += 8) {
        const int d = node0 + n;
        const float2 as2 = *reinterpret_cast<const float2*>(a_src + 2 * d);
        const float exs0 = __expf(lrelu(as2.x + adst[n][0]));
        const float exs1 = __expf(lrelu(as2.y + adst[n][1]));
        const int start = off[n << 4];
        const int cnt1  = off[(n << 4) + 16] - start + 1;  // +1 self loop

        float acc[8];
        #pragma unroll
        for (int i = 0; i < 8; ++i) acc[i] = 0.f;
        float den = 0.f;

        #pragma unroll 4
        for (int v = q; v < cnt1; v += 4) {
            int s; float ex;
            if (v == 0) {
                s = d;  ex = hd ? exs1 : exs0;
            } else {
                const int2 r = lsorted[start + v - 1];
                s = r.y;
                const unsigned eb = (unsigned)r.x;
                ex = h2f_bits(hd ? (unsigned short)(eb >> 16)
                                 : (unsigned short)(eb & 0xFFFFu));
            }
            const ushort8_v hv = *reinterpret_cast<const ushort8_v*>(
                hb + (size_t)s * 128 + sl * 8);
            den += ex;
            #pragma unroll
            for (int i = 0; i < 8; ++i)
                acc[i] = fmaf(ex, bf2f(hv[i]), acc[i]);
        }

        #pragma unroll
        for (int o = 16; o <= 32; o <<= 1) {
            #pragma unroll
            for (int i = 0; i < 8; ++i) acc[i] += __shfl_xor(acc[i], o);
            den += __shfl_xor(den, o);
        }

        if (q == 0) {
            const float inv = 1.f / (den + 1e-16f);
            float4 o0, o1;
            o0.x = acc[0] * inv + bias[sl * 8 + 0];
            o0.y = acc[1] * inv + bias[sl * 8 + 1];
            o0.z = acc[2] * inv + bias[sl * 8 + 2];
            o0.w = acc[3] * inv + bias[sl * 8 + 3];
            o1.x = acc[4] * inv + bias[sl * 8 + 4];
            o1.y = acc[5] * inv + bias[sl * 8 + 5];
            o1.z = acc[6] * inv + bias[sl * 8 + 6];
            o1.w = acc[7] * inv + bias[sl * 8 + 7];
            float* op = out + (size_t)d * 128 + sl * 8;
            *reinterpret_cast<float4*>(op)     = o0;
            *reinterpret_cast<float4*>(op + 4) = o1;
        }
    }
}

extern "C" void kernel_launch(void* const* d_in, const int* in_sizes, int n_in,
                              void* d_out, int out_size, void* d_ws, size_t ws_size,
                              hipStream_t stream) {
    const int*   edge  = (const int*)  d_in[0];   // (2,E) int32
    const float* users = (const float*)d_in[1];   // (N_USERS,64) f32
    const float* items = (const float*)d_in[2];   // (N_ITEMS,64) f32
    const float* W     = (const float*)d_in[3];   // (64,128) f32
    const float* att_s = (const float*)d_in[4];   // (2,64) f32
    const float* att_d = (const float*)d_in[5];   // (2,64) f32
    const float* bias  = (const float*)d_in[6];   // (128,) f32

    const int E       = in_sizes[0] / 2;
    const int n_users = in_sizes[1] / 64;
    const int n_items = in_sizes[2] / 64;
    const int N       = n_users + n_items;
    const int nbuckets = (N + BNODES - 1) >> BSHIFT;   // 1034

    float* out = (float*)d_out;

    // Workspace layout (8-B alignment maintained):
    // hb (N*128 bf16) | stage (MAXB*CAP int, fixed-capacity regions)
    // | a_src | a_dst | tails
    char* ws = (char*)d_ws;
    unsigned short* hb = (unsigned short*)ws;
    ws += (size_t)N * 128 * sizeof(unsigned short);
    int*   stage    = (int*)ws;    ws += (size_t)MAXB * CAP * sizeof(int);
    float* a_src    = (float*)ws;  ws += (size_t)N * 2 * sizeof(float);
    float* a_dst    = (float*)ws;  ws += (size_t)N * 2 * sizeof(float);
    int*   tails    = (int*)ws;

    const int* src = edge;
    const int* dst = edge + E;

    hipMemsetAsync(tails, 0, MAXB * sizeof(int), stream);

    const int nbin = (E + BIN_E - 1) / BIN_E;          // 489
    const int nxf  = (N + 127) / 128;                  // 517
    const int ntotal = nbin + nxf;
    k_xform_bin<<<ntotal, 512, 0, stream>>>(
        users, items, W, att_s, att_d, hb, a_src, a_dst,
        src, dst, tails, stage, E, nbuckets, n_users, N, nxf, ntotal);

    k_sort_gather<<<nbuckets, 512, 0, stream>>>(
        stage, tails, a_src, a_dst, hb, bias, out, N);
}

// Round 9
// 210.043 us; speedup vs baseline: 1.1290x; 1.0883x over previous
//
#include <hip/hip_runtime.h>
#include <hip/hip_fp16.h>
#include <math.h>

#define NEG_SLOPE 0.2f
#define BSHIFT 6         // 64-node buckets
#define BNODES 64
#define MAXB 1056        // >= nbuckets = ceil(N/64) = 1034
#define CAP 2816         // records per bucket region; mean 1936, sigma 44 (+20 sigma)
#define BIN_E 4096       // edges per bin block (round-8 verified: fewer device
                         // atomics + 16B bursts vs 2048)
#define SG_THREADS 256   // round-9: 4-wave sg blocks -> 6 blocks/CU (24 waves)
#define RPT (CAP / SG_THREADS)   // 11 records per thread (reg-staged)

typedef unsigned short ushort8_v __attribute__((ext_vector_type(8)));
typedef short  short8_v  __attribute__((ext_vector_type(8)));
typedef float  float4_v  __attribute__((ext_vector_type(4)));

__device__ __forceinline__ unsigned short f2bf(float f) {
    unsigned u = __float_as_uint(f);
    u = (u + 0x7FFFu + ((u >> 16) & 1u)) >> 16;    // round-nearest-even
    return (unsigned short)u;
}
__device__ __forceinline__ float bf2f(unsigned short b) {
    return __uint_as_float(((unsigned)b) << 16);
}
__device__ __forceinline__ float lrelu(float x) {
    return x > 0.f ? x : NEG_SLOPE * x;
}
__device__ __forceinline__ unsigned f2h_bits(float f) {
    __half_raw hr = __half_raw(__float2half_rn(f));
    return (unsigned)hr.x;
}
__device__ __forceinline__ float h2f_bits(unsigned short u) {
    __half_raw hr; hr.x = u;
    return __half2float(__half(hr));
}

// ---------------------------------------------------------------------------
// K1 (fused, Bresenham-interleaved roles): bin blocks build 4B records
//   rec = src | (dst&63)<<17
// via LDS counting-sort (4096 edges/block) into fixed-capacity bucket
// regions stage[b*CAP...]; ~1 device atomic per (block, nonempty bucket).
// runbase folded into runoff as a shift (idx = shift[b] + local_pos).
// Transform blocks: node MFMA transform + attention logits; hb staged in
// LDS, coalesced 16B flush. Bresenham interleave keeps both roles
// co-resident from dispatch 0.
// LDS union: bin 37.2KB vs tile 33.3KB -> 37.2KB static, 4 blocks/CU.
// Layouts (verified m89/m91/m120): A[m=lane&15][k=quad*8+j],
// B[k=quad*8+j][n=lane&15], C: col=lane&15, row=quad*4+reg.
// ---------------------------------------------------------------------------
__global__ __launch_bounds__(512) void k_xform_bin(
        const float* __restrict__ users,
        const float* __restrict__ items,
        const float* __restrict__ W,
        const float* __restrict__ att_src,
        const float* __restrict__ att_dst,
        unsigned short* __restrict__ hb,
        float* __restrict__ a_src,
        float* __restrict__ a_dst,
        const int* __restrict__ src,
        const int* __restrict__ dst,
        int* __restrict__ tails,
        int* __restrict__ stage_g,
        int nedges, int nbuckets, int n_users, int N,
        int nxf, int ntotal)
{
    __shared__ __align__(16) char smem[3 * MAXB * 4 + BIN_E * 4 + BIN_E * 2];

    const int tid  = threadIdx.x;          // 0..511
    const int lane = tid & 63;
    const int wid  = tid >> 6;             // 0..7

    // Bresenham role split: exactly nxf transform blocks, evenly interleaved
    const int bid = blockIdx.x;
    const long long num = (long long)nxf;
    const int xf_before = (int)(((long long)bid * num) / ntotal);
    const bool is_xf = ((((long long)(bid + 1) * num) / ntotal) > xf_before);

    if (!is_xf) {
        // ---------------- bin part ----------------
        const int bin_id = bid - xf_before;
        int* cnt     = (int*)smem;                 // [MAXB]
        int* runoff  = cnt + MAXB;                 // becomes shift later
        int* cursor  = runoff + MAXB;
        int* stage   = cursor + MAXB;              // [BIN_E]
        unsigned short* sb = (unsigned short*)(stage + BIN_E);  // [BIN_E]

        const int base = bin_id * BIN_E;
        const int nvalid = min(BIN_E, nedges - base);

        for (int i = tid; i < nbuckets; i += 512) cnt[i] = 0;
        __syncthreads();

        int myrec[BIN_E / 512];
        int myb[BIN_E / 512];
        #pragma unroll
        for (int k = 0; k < BIN_E / 512; ++k) {
            int i = base + k * 512 + tid;
            if (i < nedges) {
                const int d = dst[i];
                myrec[k] = src[i] | ((d & (BNODES - 1)) << 17);
                myb[k] = d >> BSHIFT;
                atomicAdd(&cnt[myb[k]], 1);
            } else {
                myb[k] = -1;
            }
        }
        __syncthreads();

        if (wid == 0) {
            int running = 0;
            for (int b2 = 0; b2 < nbuckets; b2 += 64) {
                int idx = b2 + lane;
                int v = (idx < nbuckets) ? cnt[idx] : 0;
                int incl = v;
                #pragma unroll
                for (int off = 1; off < 64; off <<= 1) {
                    int t = __shfl_up(incl, off);
                    if (lane >= off) incl += t;
                }
                if (idx < nbuckets) runoff[idx] = running + incl - v;
                running += __shfl(incl, 63);
            }
        }
        __syncthreads();

        for (int i = tid; i < nbuckets; i += 512) cursor[i] = runoff[i];
        __syncthreads();

        #pragma unroll
        for (int k = 0; k < BIN_E / 512; ++k) {
            if (myb[k] >= 0) {
                int pos = atomicAdd(&cursor[myb[k]], 1);
                stage[pos] = myrec[k];
                sb[pos] = (unsigned short)myb[k];
            }
        }

        // tails bump + fold runbase into runoff: shift = runbase - runoff
        for (int i = tid; i < nbuckets; i += 512)
            if (cnt[i] > 0) {
                const int rb = atomicAdd(&tails[i], cnt[i]);
                runoff[i] = rb - runoff[i];
            }
        __syncthreads();

        for (int i = tid; i < nvalid; i += 512) {
            const int b = sb[i];
            const int idx = runoff[b] + i;         // shift + local pos
            if (idx < CAP)
                stage_g[(size_t)b * CAP + idx] = stage[i];
        }
        return;
    }

    // ---------------- transform part ----------------
    unsigned short (*tile)[130] = (unsigned short (*)[130])smem;
    const int blk  = xf_before;              // transform block id 0..nxf-1
    const int quad = lane >> 4;              // 0..3
    const int l16  = lane & 15;
    const int tb   = blk * 128 + wid * 16;   // tile base node

    // B fragments: bfrag[t][h2] holds W[k = h2*32+quad*8+j][t*16 + l16]
    short8_v bfrag[8][2];
    #pragma unroll
    for (int t = 0; t < 8; ++t)
        #pragma unroll
        for (int h2 = 0; h2 < 2; ++h2)
            #pragma unroll
            for (int j = 0; j < 8; ++j)
                bfrag[t][h2][j] = (short)f2bf(
                    W[(h2 * 32 + quad * 8 + j) * 128 + t * 16 + l16]);

    float atts[8], attd[8];
    #pragma unroll
    for (int t = 0; t < 8; ++t) {
        atts[t] = att_src[t * 16 + l16];
        attd[t] = att_dst[t * 16 + l16];
    }

    const int arow = tb + l16;
    short8_v a0 = (short8_v)0, a1 = (short8_v)0;
    if (arow < N) {
        const float* xr = (arow < n_users)
            ? (users + (size_t)arow * 64)
            : (items + (size_t)(arow - n_users) * 64);
        const float4_v x0 = *reinterpret_cast<const float4_v*>(xr + quad * 8);
        const float4_v x1 = *reinterpret_cast<const float4_v*>(xr + quad * 8 + 4);
        const float4_v x2 = *reinterpret_cast<const float4_v*>(xr + 32 + quad * 8);
        const float4_v x3 = *reinterpret_cast<const float4_v*>(xr + 32 + quad * 8 + 4);
        #pragma unroll
        for (int j = 0; j < 4; ++j) {
            a0[j]     = (short)f2bf(x0[j]);
            a0[j + 4] = (short)f2bf(x1[j]);
            a1[j]     = (short)f2bf(x2[j]);
            a1[j + 4] = (short)f2bf(x3[j]);
        }
    }

    float4_v acc[8];
    #pragma unroll
    for (int t = 0; t < 8; ++t) {
        acc[t] = (float4_v)0.f;
        acc[t] = __builtin_amdgcn_mfma_f32_16x16x32_bf16(a0, bfrag[t][0], acc[t], 0, 0, 0);
        acc[t] = __builtin_amdgcn_mfma_f32_16x16x32_bf16(a1, bfrag[t][1], acc[t], 0, 0, 0);
    }

    const int wrow0 = tb + quad * 4;
    float s0[4] = {0,0,0,0}, s1[4] = {0,0,0,0};
    float d0[4] = {0,0,0,0}, d1[4] = {0,0,0,0};
    #pragma unroll
    for (int t = 0; t < 8; ++t) {
        #pragma unroll
        for (int r = 0; r < 4; ++r) {
            const float v = acc[t][r];
            if (t < 4) { s0[r] = fmaf(v, atts[t], s0[r]);
                         d0[r] = fmaf(v, attd[t], d0[r]); }
            else       { s1[r] = fmaf(v, atts[t], s1[r]);
                         d1[r] = fmaf(v, attd[t], d1[r]); }
            tile[wid * 16 + quad * 4 + r][t * 16 + l16] = f2bf(v);
        }
    }

    #pragma unroll
    for (int off = 1; off < 16; off <<= 1) {
        #pragma unroll
        for (int r = 0; r < 4; ++r) {
            s0[r] += __shfl_xor(s0[r], off);
            s1[r] += __shfl_xor(s1[r], off);
            d0[r] += __shfl_xor(d0[r], off);
            d1[r] += __shfl_xor(d1[r], off);
        }
    }
    if (l16 == 0) {
        #pragma unroll
        for (int r = 0; r < 4; ++r) {
            const int row = wrow0 + r;
            if (row < N) {
                a_src[row * 2]     = s0[r];
                a_src[row * 2 + 1] = s1[r];
                a_dst[row * 2]     = d0[r];
                a_dst[row * 2 + 1] = d1[r];
            }
        }
    }

    // coalesced hb flush: 16B per lane
    __syncthreads();
    const int base_node = blk * 128;
    const int nrem = min(128, N - base_node);
    for (int k = tid; k < nrem * 16; k += 512) {
        const int n = k >> 4, g = k & 15;
        ushort8_v v;
        #pragma unroll
        for (int j = 0; j < 8; ++j) v[j] = tile[n][g * 8 + j];
        *reinterpret_cast<ushort8_v*>(
            hb + (size_t)(base_node + n) * 128 + g * 8) = v;
    }
}

// ---------------------------------------------------------------------------
// K2: fused within-bucket sort + gather. Round-9: node-only sort key
// (round-8's src-slice key falsified: FETCH unchanged 208MB, scan cost
// +5.5us) and 256-thr blocks (4 waves). 512-thr blocks were hard-capped at
// 4 blocks/CU by the 32-wave limit; 256-thr + 23.8KB LDS -> 6 blocks/CU
// (24 waves), so each block's serial sort prologue hides behind 5 peers'
// gathers, and the 4.04-round grid tail is finer-grained.
// Phase 1: records reg-staged (RPT=11/thread) while histogramming (deletes
// the 8MB global re-read). Phase 2: exp once per edge from regs, pack
// f16x2, scatter int2{exbits,src} into per-node order in LDS. Phase 3:
// verified quarter-wave gather loop, byte-identical (wave walks 16 nodes).
// ---------------------------------------------------------------------------
__global__ __launch_bounds__(SG_THREADS) void k_sort_gather(
        const int* __restrict__ stage_g,
        const int* __restrict__ tails,
        const float* __restrict__ a_src,
        const float* __restrict__ a_dst,
        const unsigned short* __restrict__ hb,
        const float* __restrict__ bias,
        float* __restrict__ out,
        int N)
{
    __shared__ int cnt[BNODES];
    __shared__ int off[BNODES];
    __shared__ int cursor[BNODES];
    __shared__ float adst[BNODES][2];
    __shared__ int2 lsorted[CAP];

    const int b    = blockIdx.x;
    const int tid  = threadIdx.x;          // 0..255
    const int lane = tid & 63;
    const int wid  = tid >> 6;             // 0..3
    const int node0  = b << BSHIFT;
    const int nnodes = min(BNODES, N - node0);
    const int nrec = min(tails[b], CAP);
    const int* bucket = stage_g + (size_t)b * CAP;

    if (tid < BNODES) {
        cnt[tid] = 0;
        if (tid < nnodes) {
            const float2 ad = *reinterpret_cast<const float2*>(
                a_dst + 2 * (node0 + tid));
            adst[tid][0] = ad.x;
            adst[tid][1] = ad.y;
        } else {
            adst[tid][0] = adst[tid][1] = 0.f;
        }
    }
    __syncthreads();

    // phase 1: single global pass -> registers + per-node histogram
    int myrec[RPT];
    #pragma unroll
    for (int k = 0; k < RPT; ++k) {
        const int i = k * SG_THREADS + tid;
        if (i < nrec) {
            const int r = bucket[i];
            myrec[k] = r;                          // bits 0..22 -> >= 0
            atomicAdd(&cnt[(r >> 17) & (BNODES - 1)], 1);
        } else {
            myrec[k] = -1;
        }
    }
    __syncthreads();

    if (wid == 0) {
        const int v = cnt[lane];
        int incl = v;
        #pragma unroll
        for (int o = 1; o < 64; o <<= 1) {
            int t = __shfl_up(incl, o);
            if (lane >= o) incl += t;
        }
        off[lane] = incl - v;
        cursor[lane] = incl - v;
    }
    __syncthreads();

    // phase 2: exp once per edge (from regs) + scatter into per-node order
    #pragma unroll
    for (int k = 0; k < RPT; ++k) {
        const int r = myrec[k];
        if (r >= 0) {
            const int s = r & 0x1FFFF;
            const int n = (r >> 17) & (BNODES - 1);
            const float2 as2 = *reinterpret_cast<const float2*>(a_src + 2 * s);
            const unsigned e0 = f2h_bits(__expf(lrelu(as2.x + adst[n][0])));
            const unsigned e1 = f2h_bits(__expf(lrelu(as2.y + adst[n][1])));
            const int pos = atomicAdd(&cursor[n], 1);
            if (pos < CAP) {
                int2 rec;
                rec.x = (int)((e1 << 16) | e0);
                rec.y = s;
                lsorted[pos] = rec;
            }
        }
    }
    __syncthreads();

    // phase 3: gather -- wave per node, quarter-wave per edge, 4 in flight
    // + unroll 4. Lane sl owns channels sl*8..sl*8+7. (round-4 verified)
    const int q  = lane >> 4;
    const int sl = lane & 15;
    const int hd = sl >> 3;

    for (int n = wid; n < nnodes; n += 4) {
        const int d = node0 + n;
        const float2 as2 = *reinterpret_cast<const float2*>(a_src + 2 * d);
        const float exs0 = __expf(lrelu(as2.x + adst[n][0]));
        const float exs1 = __expf(lrelu(as2.y + adst[n][1]));
        const int start = off[n];
        const int cnt1  = cnt[n] + 1;      // +1 for self loop

        float acc[8];
        #pragma unroll
        for (int i = 0; i < 8; ++i) acc[i] = 0.f;
        float den = 0.f;

        #pragma unroll 4
        for (int v = q; v < cnt1; v += 4) {
            int s; float ex;
            if (v == 0) {
                s = d;  ex = hd ? exs1 : exs0;
            } else {
                const int2 r = lsorted[start + v - 1];
                s = r.y;
                const unsigned eb = (unsigned)r.x;
                ex = h2f_bits(hd ? (unsigned short)(eb >> 16)
                                 : (unsigned short)(eb & 0xFFFFu));
            }
            const ushort8_v hv = *reinterpret_cast<const ushort8_v*>(
                hb + (size_t)s * 128 + sl * 8);
            den += ex;
            #pragma unroll
            for (int i = 0; i < 8; ++i)
                acc[i] = fmaf(ex, bf2f(hv[i]), acc[i]);
        }

        #pragma unroll
        for (int o = 16; o <= 32; o <<= 1) {
            #pragma unroll
            for (int i = 0; i < 8; ++i) acc[i] += __shfl_xor(acc[i], o);
            den += __shfl_xor(den, o);
        }

        if (q == 0) {
            const float inv = 1.f / (den + 1e-16f);
            float4 o0, o1;
            o0.x = acc[0] * inv + bias[sl * 8 + 0];
            o0.y = acc[1] * inv + bias[sl * 8 + 1];
            o0.z = acc[2] * inv + bias[sl * 8 + 2];
            o0.w = acc[3] * inv + bias[sl * 8 + 3];
            o1.x = acc[4] * inv + bias[sl * 8 + 4];
            o1.y = acc[5] * inv + bias[sl * 8 + 5];
            o1.z = acc[6] * inv + bias[sl * 8 + 6];
            o1.w = acc[7] * inv + bias[sl * 8 + 7];
            float* op = out + (size_t)d * 128 + sl * 8;
            *reinterpret_cast<float4*>(op)     = o0;
            *reinterpret_cast<float4*>(op + 4) = o1;
        }
    }
}

extern "C" void kernel_launch(void* const* d_in, const int* in_sizes, int n_in,
                              void* d_out, int out_size, void* d_ws, size_t ws_size,
                              hipStream_t stream) {
    const int*   edge  = (const int*)  d_in[0];   // (2,E) int32
    const float* users = (const float*)d_in[1];   // (N_USERS,64) f32
    const float* items = (const float*)d_in[2];   // (N_ITEMS,64) f32
    const float* W     = (const float*)d_in[3];   // (64,128) f32
    const float* att_s = (const float*)d_in[4];   // (2,64) f32
    const float* att_d = (const float*)d_in[5];   // (2,64) f32
    const float* bias  = (const float*)d_in[6];   // (128,) f32

    const int E       = in_sizes[0] / 2;
    const int n_users = in_sizes[1] / 64;
    const int n_items = in_sizes[2] / 64;
    const int N       = n_users + n_items;
    const int nbuckets = (N + BNODES - 1) >> BSHIFT;   // 1034

    float* out = (float*)d_out;

    // Workspace layout (8-B alignment maintained):
    // hb (N*128 bf16) | stage (MAXB*CAP int, fixed-capacity regions)
    // | a_src | a_dst | tails
    char* ws = (char*)d_ws;
    unsigned short* hb = (unsigned short*)ws;
    ws += (size_t)N * 128 * sizeof(unsigned short);
    int*   stage    = (int*)ws;    ws += (size_t)MAXB * CAP * sizeof(int);
    float* a_src    = (float*)ws;  ws += (size_t)N * 2 * sizeof(float);
    float* a_dst    = (float*)ws;  ws += (size_t)N * 2 * sizeof(float);
    int*   tails    = (int*)ws;

    const int* src = edge;
    const int* dst = edge + E;

    hipMemsetAsync(tails, 0, MAXB * sizeof(int), stream);

    const int nbin = (E + BIN_E - 1) / BIN_E;          // 489
    const int nxf  = (N + 127) / 128;                  // 517
    const int ntotal = nbin + nxf;
    k_xform_bin<<<ntotal, 512, 0, stream>>>(
        users, items, W, att_s, att_d, hb, a_src, a_dst,
        src, dst, tails, stage, E, nbuckets, n_users, N, nxf, ntotal);

    k_sort_gather<<<nbuckets, SG_THREADS, 0, stream>>>(
        stage, tails, a_src, a_dst, hb, bias, out, N);
}